// Round 9
// baseline (403.281 us; speedup 1.0000x reference)
//
#include <hip/hip_runtime.h>
#include <hip/hip_bf16.h>

#define NODES   100000
#define EDGES   1600000
#define INDIM   128
#define HID     64
#define NCLS    40
#define NEG_BIG_F (-9000000000000000.0f)
#define SENTINEL  (-3.0e38f)

#define BN       512                 // dst-nodes per coarse bucket (dst >> 9)
#define NBUCK    196                 // ceil(100000/512)
#define CHUNK    7168                // edges per phase-A block
#define NCHUNK   ((EDGES + CHUNK - 1) / CHUNK)   // 224
#define BCAP     8960                // phase-B stage capacity (mean 8192)
#define MZB      1024                // edge-parallel mz blocks

static __device__ __forceinline__ float b2f(__hip_bfloat16 h){
    return __bfloat162float(h);
}
static __device__ __forceinline__ float bits2f(unsigned int b){
    union { unsigned int u; float f; } v; v.u = b << 16; return v.f;
}
static __device__ __forceinline__ unsigned short f2b(float f){
    __hip_bfloat16 h = __float2bfloat16(f);
    return *reinterpret_cast<unsigned short*>(&h);
}
static __device__ __forceinline__ float ldin(const void* p, int i, bool f32){
    return f32 ? ((const float*)p)[i] : b2f(((const __hip_bfloat16*)p)[i]);
}
static __device__ __forceinline__ void unpack8(uint4 u, float* o){
    o[0]=bits2f(u.x & 0xffffu); o[1]=bits2f(u.x >> 16);
    o[2]=bits2f(u.y & 0xffffu); o[3]=bits2f(u.y >> 16);
    o[4]=bits2f(u.z & 0xffffu); o[5]=bits2f(u.z >> 16);
    o[6]=bits2f(u.w & 0xffffu); o[7]=bits2f(u.w >> 16);
}
static __device__ __forceinline__ int ld_src(const int* ei, int i, bool i64){
    return i64 ? ei[2*i] : ei[i];
}
static __device__ __forceinline__ int ld_dst(const int* ei, int i, bool i64){
    return i64 ? ei[2*(EDGES + i)] : ei[EDGES + i];
}

// flags[0]=1 if floats are fp32; flags[1]=1 if edge_index is int64
__global__ __launch_bounds__(256) void k_detect(const unsigned* __restrict__ xw,
                                                const unsigned* __restrict__ eiw,
                                                int* __restrict__ flags){
    __shared__ int s1[256], s2[256];
    int t = threadIdx.x;
    int c1 = 0, c2 = 0;
    for(int i = t; i < 1024; i += 256){
        unsigned e = (xw[i] >> 23) & 0xffu;
        c1 += (e >= 90u && e <= 160u) ? 1 : 0;
        c2 += (eiw[2*i + 1] == 0u) ? 1 : 0;
    }
    s1[t] = c1; s2[t] = c2; __syncthreads();
    for(int off = 128; off > 0; off >>= 1){
        if(t < off){ s1[t] += s1[t+off]; s2[t] += s2[t+off]; }
        __syncthreads();
    }
    if(t == 0){ flags[0] = (s1[0] > 512) ? 1 : 0; flags[1] = (s2[0] > 512) ? 1 : 0; }
}

// ---------------- bucket histogram ----------------
__global__ __launch_bounds__(256) void k_bhist(const int* __restrict__ ei,
                                               const int* __restrict__ flags,
                                               int* __restrict__ bdeg){
    __shared__ int sh[NBUCK];
    bool i64 = flags[1] != 0;
    int t = threadIdx.x;
    for(int i = t; i < NBUCK; i += 256) sh[i] = 0;
    __syncthreads();
    int i = blockIdx.x*256 + t;
    int stride = gridDim.x*256;
    for(; i < EDGES; i += stride) atomicAdd(&sh[ld_dst(ei, i, i64) >> 9], 1);
    __syncthreads();
    for(int b = t; b < NBUCK; b += 256) if(sh[b]) atomicAdd(&bdeg[b], sh[b]);
}

__global__ void k_bscan(const int* __restrict__ bdeg, int* __restrict__ bstart,
                        int* __restrict__ bcursor){
    if(threadIdx.x == 0){
        int acc = 0;
        for(int b = 0; b < NBUCK; b++){
            bstart[b] = acc; bcursor[b] = acc; acc += bdeg[b];
        }
        bstart[NBUCK] = acc;
    }
}

// ---------------- phase A: LDS-binned coarse scatter ----------------
__global__ __launch_bounds__(256) void k_bucket_scatter(const int* __restrict__ ei,
    const int* __restrict__ flags, int* __restrict__ bcursor, int2* __restrict__ tmp){
    __shared__ int  sCnt[NBUCK], sScan[NBUCK], sCur[NBUCK], sGofs[NBUCK];
    __shared__ int2 stage[CHUNK];
    bool i64 = flags[1] != 0;
    int t = threadIdx.x;
    int base = blockIdx.x * CHUNK;
    int n = EDGES - base; if(n > CHUNK) n = CHUNK; if(n <= 0) return;

    for(int b = t; b < NBUCK; b += 256) sCnt[b] = 0;
    __syncthreads();
    for(int j = t; j < n; j += 256)
        atomicAdd(&sCnt[ld_dst(ei, base + j, i64) >> 9], 1);
    __syncthreads();
    for(int b = t; b < NBUCK; b += 256) sScan[b] = sCnt[b];
    __syncthreads();
    for(int off = 1; off < NBUCK; off <<= 1){
        int v = 0;
        if(t < NBUCK && t >= off) v = sScan[t - off];
        __syncthreads();
        if(t < NBUCK) sScan[t] += v;
        __syncthreads();
    }
    if(t < NBUCK){
        int excl = sScan[t] - sCnt[t];
        sCur[t]  = excl;
        sGofs[t] = sCnt[t] ? atomicAdd(&bcursor[t], sCnt[t]) : 0;
    }
    __syncthreads();
    for(int j = t; j < n; j += 256){
        int src = ld_src(ei, base + j, i64);
        int dst = ld_dst(ei, base + j, i64);
        int pos = atomicAdd(&sCur[dst >> 9], 1);
        stage[pos] = make_int2(src, dst);
    }
    __syncthreads();
    for(int i = t; i < n; i += 256){
        int2 e = stage[i];
        int  b = e.y >> 9;
        int  excl = sScan[b] - sCnt[b];
        tmp[(size_t)sGofs[b] + (i - excl)] = e;
    }
}

// ---------------- phase B: per-bucket counting sort -> col + did + rowst ----------------
__global__ __launch_bounds__(512) void k_bucket_sort(const int2* __restrict__ tmp,
    const int* __restrict__ bstart, int* __restrict__ col, int* __restrict__ did,
    int* __restrict__ rowst){
    __shared__ int  sCnt[BN], sScan[BN], sCur[BN];
    __shared__ int2 stage[BCAP];
    int b = blockIdx.x, t = threadIdx.x;
    int nb0 = b * BN;
    int gbase = bstart[b], gend = bstart[b+1];
    int cnt = gend - gbase;

    if(t < BN) sCnt[t] = 0;
    __syncthreads();
    for(int j = gbase + t; j < gend; j += 512)
        atomicAdd(&sCnt[tmp[j].y - nb0], 1);
    __syncthreads();
    if(t < BN) sScan[t] = sCnt[t];
    __syncthreads();
    for(int off = 1; off < BN; off <<= 1){
        int v = 0;
        if(t < BN && t >= off) v = sScan[t - off];
        __syncthreads();
        if(t < BN) sScan[t] += v;
        __syncthreads();
    }
    if(t < BN) sCur[t] = sScan[t] - sCnt[t];
    if(t < BN && (nb0 + t) < NODES) rowst[nb0 + t] = gbase + (sScan[t] - sCnt[t]);
    if(b == 0 && t == 0) rowst[NODES] = EDGES;
    __syncthreads();
    for(int j = gbase + t; j < gend; j += 512){
        int2 e = tmp[j];
        int pos = atomicAdd(&sCur[e.y - nb0], 1);
        if(pos < BCAP) stage[pos] = e;
        else { col[gbase + pos] = e.x; did[gbase + pos] = e.y; }
    }
    __syncthreads();
    int lim = (cnt < BCAP) ? cnt : BCAP;
    for(int i = t; i < lim; i += 512){
        int2 e = stage[i];
        col[gbase + i] = e.x;
        did[gbase + i] = e.y;
    }
}

// ---------------- GEMM: C[N x 64] = A[N x K] * W[K x 64] (+bias) (+score epilogue) ----------------
template<int K, int AMODE, bool WITH_BIAS, bool WITH_SCORES, bool CBF16>
__global__ __launch_bounds__(256) void k_gemm(
    const void* __restrict__ Aptr,
    const void* __restrict__ Wb,   int woff,
    const void* __restrict__ biasb,
    const void* __restrict__ attnb, int aoff,
    const int*  __restrict__ flags,
    void* __restrict__ Cout,
    float* __restrict__ s_src,
    float* __restrict__ s_dst)
{
    __shared__ float At[64][68];
    __shared__ float Wf[64][64];
    const bool wf32 = flags[0] != 0;
    const bool af32 = (AMODE == 2) ? true : wf32;
    const int t = threadIdx.x;
    const int block_row = blockIdx.x * 64;
    const int r_load = t >> 2;
    const int q_load = t & 3;
    const int grow_load = block_row + r_load;

    const int c0 = (t & 15) * 4;
    const int r0 = (t >> 4) * 4;

    float acc[4][4] = {{0.f,0.f,0.f,0.f},{0.f,0.f,0.f,0.f},{0.f,0.f,0.f,0.f},{0.f,0.f,0.f,0.f}};

    for(int kb = 0; kb < K; kb += 64){
        if(wf32){
            const float4* wv = (const float4*)Wb;
            for(int v = t; v < 1024; v += 256){
                float4 u = wv[(size_t)(woff + kb*64)/4 + v];
                int f = v*4; int k = f >> 6; int c = f & 63;
                Wf[k][c]=u.x; Wf[k][c+1]=u.y; Wf[k][c+2]=u.z; Wf[k][c+3]=u.w;
            }
        } else {
            const uint4* wv = (const uint4*)Wb;
            for(int v = t; v < 512; v += 256){
                uint4 u = wv[(size_t)(woff + kb*64)/8 + v];
                float o[8]; unpack8(u, o);
                int f = v*8; int k = f >> 6; int c = f & 63;
                #pragma unroll
                for(int j=0;j<8;j++) Wf[k][c+j] = o[j];
            }
        }
        if(af32){
            const float4* av = (const float4*)Aptr;
            #pragma unroll
            for(int i=0;i<4;i++){
                int vi = q_load + 4*i;
                int k0 = vi*4;
                float4 u = make_float4(0.f,0.f,0.f,0.f);
                if(grow_load < NODES) u = av[(size_t)grow_load*(K/4) + (kb>>2) + vi];
                At[k0+0][r_load]=u.x; At[k0+1][r_load]=u.y;
                At[k0+2][r_load]=u.z; At[k0+3][r_load]=u.w;
            }
        } else {
            const uint4* av = (const uint4*)Aptr;
            #pragma unroll
            for(int i=0;i<2;i++){
                int vi = q_load + 4*i;
                int k0 = vi*8;
                float o[8];
                if(grow_load < NODES){
                    uint4 u = av[(size_t)grow_load*(K/8) + (kb>>3) + vi];
                    unpack8(u, o);
                } else {
                    #pragma unroll
                    for(int j=0;j<8;j++) o[j]=0.f;
                }
                #pragma unroll
                for(int j=0;j<8;j++) At[k0+j][r_load] = o[j];
            }
        }
        __syncthreads();
        #pragma unroll 8
        for(int k=0;k<64;k++){
            float4 a = *(const float4*)&At[k][r0];
            float4 w = *(const float4*)&Wf[k][c0];
            float av4[4] = {a.x,a.y,a.z,a.w};
            float wv4[4] = {w.x,w.y,w.z,w.w};
            #pragma unroll
            for(int i=0;i<4;i++)
                #pragma unroll
                for(int j=0;j<4;j++)
                    acc[i][j] = fmaf(av4[i], wv4[j], acc[i][j]);
        }
        __syncthreads();
    }

    float bias[4] = {0.f,0.f,0.f,0.f};
    if constexpr (WITH_BIAS){
        #pragma unroll
        for(int j=0;j<4;j++) bias[j] = ldin(biasb, c0+j, wf32);
    }
    #pragma unroll
    for(int i=0;i<4;i++){
        int grow = block_row + r0 + i;
        if(grow < NODES){
            if constexpr (CBF16){
                ushort4 o;
                o.x = f2b(acc[i][0]+bias[0]); o.y = f2b(acc[i][1]+bias[1]);
                o.z = f2b(acc[i][2]+bias[2]); o.w = f2b(acc[i][3]+bias[3]);
                *(ushort4*)((unsigned short*)Cout + (size_t)grow*64 + c0) = o;
            } else {
                float4 o = make_float4(acc[i][0]+bias[0], acc[i][1]+bias[1],
                                       acc[i][2]+bias[2], acc[i][3]+bias[3]);
                *(float4*)((float*)Cout + (size_t)grow*64 + c0) = o;
            }
        }
    }
    if constexpr (WITH_SCORES){
        float as[4], ad[4];
        #pragma unroll
        for(int j=0;j<4;j++){
            as[j] = ldin(attnb, aoff + c0+j, wf32);
            ad[j] = ldin(attnb, aoff + 64+c0+j, wf32);
        }
        #pragma unroll
        for(int i=0;i<4;i++){
            float ps = 0.f, pd = 0.f;
            #pragma unroll
            for(int j=0;j<4;j++){ ps = fmaf(acc[i][j], as[j], ps); pd = fmaf(acc[i][j], ad[j], pd); }
            for(int off=1; off<16; off<<=1){
                ps += __shfl_xor(ps, off, 64);
                pd += __shfl_xor(pd, off, 64);
            }
            int grow = block_row + r0 + i;
            if((t & 15) == 0 && grow < NODES){ s_src[grow] = ps; s_dst[grow] = pd; }
        }
    }
}

// ---------------- edge-parallel logits + online (m,z) ----------------
__global__ __launch_bounds__(256) void k_edge_l(const int* __restrict__ col,
    const int* __restrict__ did, const float* __restrict__ ssrc,
    const float* __restrict__ sdst, float* __restrict__ l, float2* __restrict__ bmz)
{
    int tid = blockIdx.x*256 + threadIdx.x;
    int stride = gridDim.x*256;
    float m = SENTINEL, z = 0.f;
    for(int e = tid; e < EDGES; e += stride){
        float v = ssrc[col[e]] + sdst[did[e]];
        v = (v > 0.f) ? v : NEG_BIG_F;
        l[e] = v;
        if(v > m){ z = z*__expf(m - v) + 1.f; m = v; }
        else     { z += __expf(v - m); }
    }
    for(int off=1; off<64; off<<=1){
        float m2 = __shfl_xor(m, off, 64), z2 = __shfl_xor(z, off, 64);
        float M = fmaxf(m, m2);
        z = z*__expf(m - M) + z2*__expf(m2 - M);
        m = M;
    }
    __shared__ float sm[4], sz[4];
    int w = threadIdx.x >> 6;
    if((threadIdx.x & 63) == 0){ sm[w] = m; sz[w] = z; }
    __syncthreads();
    if(threadIdx.x == 0){
        for(int i=1;i<4;i++){
            float M = fmaxf(m, sm[i]);
            z = z*__expf(m - M) + sz[i]*__expf(sm[i] - M);
            m = M;
        }
        bmz[blockIdx.x] = make_float2(m, z);
    }
}

__global__ __launch_bounds__(256) void k_merge_mz(const float2* __restrict__ bmz, float2* __restrict__ MZ){
    int t = threadIdx.x;
    float m = SENTINEL, z = 0.f;
    for(int i = t; i < MZB; i += 256){
        float2 e = bmz[i];
        float M = fmaxf(m, e.x);
        z = z*__expf(m - M) + e.y*__expf(e.x - M);
        m = M;
    }
    for(int off=1; off<64; off<<=1){
        float m2 = __shfl_xor(m, off, 64), z2 = __shfl_xor(z, off, 64);
        float M = fmaxf(m, m2);
        z = z*__expf(m - M) + z2*__expf(m2 - M);
        m = M;
    }
    __shared__ float sm[4], sz[4];
    int w = t >> 6;
    if((t & 63) == 0){ sm[w] = m; sz[w] = z; }
    __syncthreads();
    if(t == 0){
        for(int i=1;i<4;i++){
            float M = fmaxf(m, sm[i]);
            z = z*__expf(m - M) + sz[i]*__expf(sm[i] - M);
            m = M;
        }
        MZ[0] = make_float2(m, 1.0f / z);
    }
}

// ---------------- att[e] = exp(l[e]-M)*invZ, in place over l ----------------
__global__ __launch_bounds__(256) void k_att(float* __restrict__ l, const float2* __restrict__ MZ){
    float2 mz = *MZ;
    float M = mz.x, invZ = mz.y;
    int tid = blockIdx.x*256 + threadIdx.x;
    int stride = gridDim.x*256;
    for(int e = tid; e < EDGES; e += stride)
        l[e] = __expf(l[e] - M) * invZ;
}

// ---------------- aggregation: one wave per dst node, 8 edge-groups, broadcast loads ----------------
__global__ __launch_bounds__(256) void k_aggregate(const unsigned short* __restrict__ wh16,
    const int* __restrict__ row_start, const int* __restrict__ col,
    const float* __restrict__ att, float* __restrict__ hout)
{
    int gw = (blockIdx.x*256 + threadIdx.x) >> 6;
    int lane = threadIdx.x & 63;
    if(gw >= NODES) return;
    int beg = row_start[gw], end = row_start[gw+1];
    int g  = lane >> 3;           // edge-group 0..7
    int c8 = (lane & 7) * 8;      // feature slice base
    float acc[8] = {0.f,0.f,0.f,0.f,0.f,0.f,0.f,0.f};
    for(int e = beg + g; e < end; e += 8){
        float a = att[e];         // 8 lanes same addr -> broadcast; wave spans 32B
        int   s = col[e];
        if(a != 0.f){
            uint4 u = *(const uint4*)&wh16[(size_t)s*64 + c8];
            acc[0] = fmaf(a, bits2f(u.x & 0xffffu), acc[0]);
            acc[1] = fmaf(a, bits2f(u.x >> 16),     acc[1]);
            acc[2] = fmaf(a, bits2f(u.y & 0xffffu), acc[2]);
            acc[3] = fmaf(a, bits2f(u.y >> 16),     acc[3]);
            acc[4] = fmaf(a, bits2f(u.z & 0xffffu), acc[4]);
            acc[5] = fmaf(a, bits2f(u.z >> 16),     acc[5]);
            acc[6] = fmaf(a, bits2f(u.w & 0xffffu), acc[6]);
            acc[7] = fmaf(a, bits2f(u.w >> 16),     acc[7]);
        }
    }
    #pragma unroll
    for(int i=0;i<8;i++){
        acc[i] += __shfl_xor(acc[i], 8, 64);
        acc[i] += __shfl_xor(acc[i], 16, 64);
        acc[i] += __shfl_xor(acc[i], 32, 64);
    }
    if(lane < 8){
        float o[8];
        #pragma unroll
        for(int i=0;i<8;i++) o[i] = (acc[i] > 0.f) ? acc[i] : expm1f(acc[i]);
        *(float4*)&hout[(size_t)gw*64 + c8 + 0] = make_float4(o[0],o[1],o[2],o[3]);
        *(float4*)&hout[(size_t)gw*64 + c8 + 4] = make_float4(o[4],o[5],o[6],o[7]);
    }
}

// ---------------- fused out-proj + elu + log_softmax, GEMM-tiled (fp32 output) ----------------
__global__ __launch_bounds__(256) void k_out(const float* __restrict__ h,
    const void* __restrict__ Wo, const void* __restrict__ bo,
    const int* __restrict__ flags, float* __restrict__ out)
{
    __shared__ float Ht[64][65];
    __shared__ float Wsh[64][44];
    __shared__ float logits[64][44];
    __shared__ float rlz[64];
    bool f32 = flags[0] != 0;
    int t = threadIdx.x;
    int block_row = blockIdx.x * 64;

    for(int i = t; i < 64*NCLS; i += 256){
        Wsh[i/NCLS][i%NCLS] = ldin(Wo, i, f32);
    }
    {
        int r_load = t >> 2, q = t & 3;
        int grow = block_row + r_load;
        const float4* hv = (const float4*)h;
        #pragma unroll
        for(int i = 0; i < 4; i++){
            int vi = q + 4*i;
            float4 u = make_float4(0.f,0.f,0.f,0.f);
            if(grow < NODES) u = hv[(size_t)grow*16 + vi];
            Ht[vi*4+0][r_load] = u.x; Ht[vi*4+1][r_load] = u.y;
            Ht[vi*4+2][r_load] = u.z; Ht[vi*4+3][r_load] = u.w;
        }
    }
    __syncthreads();

    int cg = t & 15, rg = t >> 4;
    int c0 = cg * 4, r0 = rg * 4;
    if(cg < 10){
        float acc[4][4] = {{0.f,0.f,0.f,0.f},{0.f,0.f,0.f,0.f},{0.f,0.f,0.f,0.f},{0.f,0.f,0.f,0.f}};
        #pragma unroll 8
        for(int k = 0; k < 64; k++){
            float4 a = *(const float4*)&Ht[k][r0];
            float4 w = *(const float4*)&Wsh[k][c0];
            float av4[4] = {a.x,a.y,a.z,a.w};
            float wv4[4] = {w.x,w.y,w.z,w.w};
            #pragma unroll
            for(int i=0;i<4;i++)
                #pragma unroll
                for(int j=0;j<4;j++)
                    acc[i][j] = fmaf(av4[i], wv4[j], acc[i][j]);
        }
        float b[4];
        #pragma unroll
        for(int j=0;j<4;j++) b[j] = ldin(bo, c0+j, f32);
        #pragma unroll
        for(int i=0;i<4;i++)
            #pragma unroll
            for(int j=0;j<4;j++){
                float v = acc[i][j] + b[j];
                logits[r0+i][c0+j] = (v > 0.f) ? v : expm1f(v);
            }
    }
    __syncthreads();

    {
        int r = t >> 2, qq = t & 3;
        float m = SENTINEL;
        #pragma unroll
        for(int i=0;i<10;i++) m = fmaxf(m, logits[r][qq*10 + i]);
        m = fmaxf(m, __shfl_xor(m, 1, 64));
        m = fmaxf(m, __shfl_xor(m, 2, 64));
        float s = 0.f;
        #pragma unroll
        for(int i=0;i<10;i++) s += __expf(logits[r][qq*10 + i] - m);
        s += __shfl_xor(s, 1, 64);
        s += __shfl_xor(s, 2, 64);
        if(qq == 0) rlz[r] = m + logf(s);
    }
    __syncthreads();

    for(int i = t; i < 64*NCLS; i += 256){
        int rr = i / NCLS, cc = i % NCLS;
        if(block_row + rr < NODES)
            out[(size_t)(block_row)*NCLS + i] = logits[rr][cc] - rlz[rr];
    }
}

extern "C" void kernel_launch(void* const* d_in, const int* in_sizes, int n_in,
                              void* d_out, int out_size, void* d_ws, size_t ws_size,
                              hipStream_t stream)
{
    const void* x      = d_in[0];
    const int*  ei     = (const int*)d_in[1];
    const void* emb_w  = d_in[2];
    const void* emb_b  = d_in[3];
    const void* Ws     = d_in[4];
    const void* attn_a = d_in[5];
    const void* out_w  = d_in[6];
    const void* out_b  = d_in[7];
    float* out = (float*)d_out;

    char* ws = (char*)d_ws;
    size_t off = 0;
    auto alloc = [&](size_t bytes)->char*{
        char* p = ws + off;
        off = (off + bytes + 255) & ~(size_t)255;
        return p;
    };
    int*    flags   = (int*)   alloc(256);
    float*  h       = (float*) alloc((size_t)NODES*HID*4);   // aliased as phase-A tmp
    unsigned short* wh16 = (unsigned short*)alloc((size_t)NODES*HID*2);
    float*  ssrc    = (float*) alloc((size_t)NODES*4);
    float*  sdst    = (float*) alloc((size_t)NODES*4);
    int*    rowst   = (int*)   alloc((size_t)(NODES+1)*4);
    int*    col     = (int*)   alloc((size_t)EDGES*4);
    int*    did     = (int*)   alloc((size_t)EDGES*4);
    float*  l       = (float*) alloc((size_t)EDGES*4);
    int*    bdeg    = (int*)   alloc(NBUCK*4);
    int*    bstart  = (int*)   alloc((NBUCK+1)*4);
    int*    bcursor = (int*)   alloc(NBUCK*4);
    float2* bmz     = (float2*)alloc(MZB*8);
    float2* MZ      = (float2*)alloc(16);

    int2* tmp = (int2*)h;   // consumed before k_gemm writes h

    k_detect<<<1, 256, 0, stream>>>((const unsigned*)x, (const unsigned*)ei, flags);

    hipMemsetAsync(bdeg, 0, NBUCK*4, stream);
    k_bhist<<<256, 256, 0, stream>>>(ei, flags, bdeg);
    k_bscan<<<1, 64, 0, stream>>>(bdeg, bstart, bcursor);
    k_bucket_scatter<<<NCHUNK, 256, 0, stream>>>(ei, flags, bcursor, tmp);
    k_bucket_sort<<<NBUCK, 512, 0, stream>>>(tmp, bstart, col, did, rowst);

    k_gemm<INDIM, 0, true, false, false><<<(NODES+63)/64, 256, 0, stream>>>(
        x, emb_w, 0, emb_b, nullptr, 0, flags, h, nullptr, nullptr);

    for(int lyr=0; lyr<2; lyr++){
        k_gemm<HID, 2, false, true, true><<<(NODES+63)/64, 256, 0, stream>>>(
            h, Ws, lyr*HID*HID, nullptr, attn_a, lyr*2*HID, flags, wh16, ssrc, sdst);
        k_edge_l  <<<MZB, 256, 0, stream>>>(col, did, ssrc, sdst, l, bmz);
        k_merge_mz<<<1, 256, 0, stream>>>(bmz, MZ);
        k_att     <<<MZB, 256, 0, stream>>>(l, MZ);
        k_aggregate<<<(NODES+3)/4, 256, 0, stream>>>(wh16, rowst, col, l, h);
    }

    k_out<<<(NODES+63)/64, 256, 0, stream>>>(h, out_w, out_b, flags, out);
}

// Round 10
// 371.525 us; speedup vs baseline: 1.0855x; 1.0855x over previous
//
#include <hip/hip_runtime.h>
#include <hip/hip_bf16.h>

#define NODES   100000
#define EDGES   1600000
#define INDIM   128
#define HID     64
#define NCLS    40
#define NEG_BIG_F (-9000000000000000.0f)
#define SENTINEL  (-3.0e38f)

#define BN       512                 // dst-nodes per coarse bucket (dst >> 9)
#define NBUCK    196                 // ceil(100000/512)
#define CHUNK    7168                // edges per phase-A block
#define NCHUNK   ((EDGES + CHUNK - 1) / CHUNK)   // 224
#define BCAP     8960                // phase-B stage capacity (mean 8192)
#define MZB      1024                // edge-parallel mz blocks

static __device__ __forceinline__ float b2f(__hip_bfloat16 h){
    return __bfloat162float(h);
}
static __device__ __forceinline__ float bits2f(unsigned int b){
    union { unsigned int u; float f; } v; v.u = b << 16; return v.f;
}
static __device__ __forceinline__ unsigned short f2b(float f){
    __hip_bfloat16 h = __float2bfloat16(f);
    return *reinterpret_cast<unsigned short*>(&h);
}
static __device__ __forceinline__ float ldin(const void* p, int i, bool f32){
    return f32 ? ((const float*)p)[i] : b2f(((const __hip_bfloat16*)p)[i]);
}
// fast ELU: expm1f is a ~30-instruction libm expansion; __expf(x)-1 is 3 instr,
// abs error ~1e-7 -- irrelevant vs the 7.4e-2 test threshold.
static __device__ __forceinline__ float elu_fast(float x){
    return (x > 0.f) ? x : (__expf(x) - 1.f);
}
static __device__ __forceinline__ void unpack8(uint4 u, float* o){
    o[0]=bits2f(u.x & 0xffffu); o[1]=bits2f(u.x >> 16);
    o[2]=bits2f(u.y & 0xffffu); o[3]=bits2f(u.y >> 16);
    o[4]=bits2f(u.z & 0xffffu); o[5]=bits2f(u.z >> 16);
    o[6]=bits2f(u.w & 0xffffu); o[7]=bits2f(u.w >> 16);
}
static __device__ __forceinline__ int ld_src(const int* ei, int i, bool i64){
    return i64 ? ei[2*i] : ei[i];
}
static __device__ __forceinline__ int ld_dst(const int* ei, int i, bool i64){
    return i64 ? ei[2*(EDGES + i)] : ei[EDGES + i];
}

// flags[0]=1 if floats are fp32; flags[1]=1 if edge_index is int64
__global__ __launch_bounds__(256) void k_detect(const unsigned* __restrict__ xw,
                                                const unsigned* __restrict__ eiw,
                                                int* __restrict__ flags){
    __shared__ int s1[256], s2[256];
    int t = threadIdx.x;
    int c1 = 0, c2 = 0;
    for(int i = t; i < 1024; i += 256){
        unsigned e = (xw[i] >> 23) & 0xffu;
        c1 += (e >= 90u && e <= 160u) ? 1 : 0;
        c2 += (eiw[2*i + 1] == 0u) ? 1 : 0;
    }
    s1[t] = c1; s2[t] = c2; __syncthreads();
    for(int off = 128; off > 0; off >>= 1){
        if(t < off){ s1[t] += s1[t+off]; s2[t] += s2[t+off]; }
        __syncthreads();
    }
    if(t == 0){ flags[0] = (s1[0] > 512) ? 1 : 0; flags[1] = (s2[0] > 512) ? 1 : 0; }
}

// ---------------- bucket histogram ----------------
__global__ __launch_bounds__(256) void k_bhist(const int* __restrict__ ei,
                                               const int* __restrict__ flags,
                                               int* __restrict__ bdeg){
    __shared__ int sh[NBUCK];
    bool i64 = flags[1] != 0;
    int t = threadIdx.x;
    for(int i = t; i < NBUCK; i += 256) sh[i] = 0;
    __syncthreads();
    int i = blockIdx.x*256 + t;
    int stride = gridDim.x*256;
    for(; i < EDGES; i += stride) atomicAdd(&sh[ld_dst(ei, i, i64) >> 9], 1);
    __syncthreads();
    for(int b = t; b < NBUCK; b += 256) if(sh[b]) atomicAdd(&bdeg[b], sh[b]);
}

__global__ void k_bscan(const int* __restrict__ bdeg, int* __restrict__ bstart,
                        int* __restrict__ bcursor){
    if(threadIdx.x == 0){
        int acc = 0;
        for(int b = 0; b < NBUCK; b++){
            bstart[b] = acc; bcursor[b] = acc; acc += bdeg[b];
        }
        bstart[NBUCK] = acc;
    }
}

// ---------------- phase A: LDS-binned coarse scatter ----------------
__global__ __launch_bounds__(256) void k_bucket_scatter(const int* __restrict__ ei,
    const int* __restrict__ flags, int* __restrict__ bcursor, int2* __restrict__ tmp){
    __shared__ int  sCnt[NBUCK], sScan[NBUCK], sCur[NBUCK], sGofs[NBUCK];
    __shared__ int2 stage[CHUNK];
    bool i64 = flags[1] != 0;
    int t = threadIdx.x;
    int base = blockIdx.x * CHUNK;
    int n = EDGES - base; if(n > CHUNK) n = CHUNK; if(n <= 0) return;

    for(int b = t; b < NBUCK; b += 256) sCnt[b] = 0;
    __syncthreads();
    for(int j = t; j < n; j += 256)
        atomicAdd(&sCnt[ld_dst(ei, base + j, i64) >> 9], 1);
    __syncthreads();
    for(int b = t; b < NBUCK; b += 256) sScan[b] = sCnt[b];
    __syncthreads();
    for(int off = 1; off < NBUCK; off <<= 1){
        int v = 0;
        if(t < NBUCK && t >= off) v = sScan[t - off];
        __syncthreads();
        if(t < NBUCK) sScan[t] += v;
        __syncthreads();
    }
    if(t < NBUCK){
        int excl = sScan[t] - sCnt[t];
        sCur[t]  = excl;
        sGofs[t] = sCnt[t] ? atomicAdd(&bcursor[t], sCnt[t]) : 0;
    }
    __syncthreads();
    for(int j = t; j < n; j += 256){
        int src = ld_src(ei, base + j, i64);
        int dst = ld_dst(ei, base + j, i64);
        int pos = atomicAdd(&sCur[dst >> 9], 1);
        stage[pos] = make_int2(src, dst);
    }
    __syncthreads();
    for(int i = t; i < n; i += 256){
        int2 e = stage[i];
        int  b = e.y >> 9;
        int  excl = sScan[b] - sCnt[b];
        tmp[(size_t)sGofs[b] + (i - excl)] = e;
    }
}

// ---------------- phase B: per-bucket counting sort -> col + did + rowst ----------------
__global__ __launch_bounds__(512) void k_bucket_sort(const int2* __restrict__ tmp,
    const int* __restrict__ bstart, int* __restrict__ col, int* __restrict__ did,
    int* __restrict__ rowst){
    __shared__ int  sCnt[BN], sScan[BN], sCur[BN];
    __shared__ int2 stage[BCAP];
    int b = blockIdx.x, t = threadIdx.x;
    int nb0 = b * BN;
    int gbase = bstart[b], gend = bstart[b+1];
    int cnt = gend - gbase;

    if(t < BN) sCnt[t] = 0;
    __syncthreads();
    for(int j = gbase + t; j < gend; j += 512)
        atomicAdd(&sCnt[tmp[j].y - nb0], 1);
    __syncthreads();
    if(t < BN) sScan[t] = sCnt[t];
    __syncthreads();
    for(int off = 1; off < BN; off <<= 1){
        int v = 0;
        if(t < BN && t >= off) v = sScan[t - off];
        __syncthreads();
        if(t < BN) sScan[t] += v;
        __syncthreads();
    }
    if(t < BN) sCur[t] = sScan[t] - sCnt[t];
    if(t < BN && (nb0 + t) < NODES) rowst[nb0 + t] = gbase + (sScan[t] - sCnt[t]);
    if(b == 0 && t == 0) rowst[NODES] = EDGES;
    __syncthreads();
    for(int j = gbase + t; j < gend; j += 512){
        int2 e = tmp[j];
        int pos = atomicAdd(&sCur[e.y - nb0], 1);
        if(pos < BCAP) stage[pos] = e;
        else { col[gbase + pos] = e.x; did[gbase + pos] = e.y; }
    }
    __syncthreads();
    int lim = (cnt < BCAP) ? cnt : BCAP;
    for(int i = t; i < lim; i += 512){
        int2 e = stage[i];
        col[gbase + i] = e.x;
        did[gbase + i] = e.y;
    }
}

// ---------------- GEMM: C[N x 64] = A[N x K] * W[K x 64] (+bias) (+score epilogue) ----------------
template<int K, int AMODE, bool WITH_BIAS, bool WITH_SCORES, bool CBF16>
__global__ __launch_bounds__(256) void k_gemm(
    const void* __restrict__ Aptr,
    const void* __restrict__ Wb,   int woff,
    const void* __restrict__ biasb,
    const void* __restrict__ attnb, int aoff,
    const int*  __restrict__ flags,
    void* __restrict__ Cout,
    float* __restrict__ s_src,
    float* __restrict__ s_dst)
{
    __shared__ float At[64][68];
    __shared__ float Wf[64][64];
    const bool wf32 = flags[0] != 0;
    const bool af32 = (AMODE == 2) ? true : wf32;
    const int t = threadIdx.x;
    const int block_row = blockIdx.x * 64;
    const int r_load = t >> 2;
    const int q_load = t & 3;
    const int grow_load = block_row + r_load;

    const int c0 = (t & 15) * 4;
    const int r0 = (t >> 4) * 4;

    float acc[4][4] = {{0.f,0.f,0.f,0.f},{0.f,0.f,0.f,0.f},{0.f,0.f,0.f,0.f},{0.f,0.f,0.f,0.f}};

    for(int kb = 0; kb < K; kb += 64){
        if(wf32){
            const float4* wv = (const float4*)Wb;
            for(int v = t; v < 1024; v += 256){
                float4 u = wv[(size_t)(woff + kb*64)/4 + v];
                int f = v*4; int k = f >> 6; int c = f & 63;
                Wf[k][c]=u.x; Wf[k][c+1]=u.y; Wf[k][c+2]=u.z; Wf[k][c+3]=u.w;
            }
        } else {
            const uint4* wv = (const uint4*)Wb;
            for(int v = t; v < 512; v += 256){
                uint4 u = wv[(size_t)(woff + kb*64)/8 + v];
                float o[8]; unpack8(u, o);
                int f = v*8; int k = f >> 6; int c = f & 63;
                #pragma unroll
                for(int j=0;j<8;j++) Wf[k][c+j] = o[j];
            }
        }
        if(af32){
            const float4* av = (const float4*)Aptr;
            #pragma unroll
            for(int i=0;i<4;i++){
                int vi = q_load + 4*i;
                int k0 = vi*4;
                float4 u = make_float4(0.f,0.f,0.f,0.f);
                if(grow_load < NODES) u = av[(size_t)grow_load*(K/4) + (kb>>2) + vi];
                At[k0+0][r_load]=u.x; At[k0+1][r_load]=u.y;
                At[k0+2][r_load]=u.z; At[k0+3][r_load]=u.w;
            }
        } else {
            const uint4* av = (const uint4*)Aptr;
            #pragma unroll
            for(int i=0;i<2;i++){
                int vi = q_load + 4*i;
                int k0 = vi*8;
                float o[8];
                if(grow_load < NODES){
                    uint4 u = av[(size_t)grow_load*(K/8) + (kb>>3) + vi];
                    unpack8(u, o);
                } else {
                    #pragma unroll
                    for(int j=0;j<8;j++) o[j]=0.f;
                }
                #pragma unroll
                for(int j=0;j<8;j++) At[k0+j][r_load] = o[j];
            }
        }
        __syncthreads();
        #pragma unroll 8
        for(int k=0;k<64;k++){
            float4 a = *(const float4*)&At[k][r0];
            float4 w = *(const float4*)&Wf[k][c0];
            float av4[4] = {a.x,a.y,a.z,a.w};
            float wv4[4] = {w.x,w.y,w.z,w.w};
            #pragma unroll
            for(int i=0;i<4;i++)
                #pragma unroll
                for(int j=0;j<4;j++)
                    acc[i][j] = fmaf(av4[i], wv4[j], acc[i][j]);
        }
        __syncthreads();
    }

    float bias[4] = {0.f,0.f,0.f,0.f};
    if constexpr (WITH_BIAS){
        #pragma unroll
        for(int j=0;j<4;j++) bias[j] = ldin(biasb, c0+j, wf32);
    }
    #pragma unroll
    for(int i=0;i<4;i++){
        int grow = block_row + r0 + i;
        if(grow < NODES){
            if constexpr (CBF16){
                ushort4 o;
                o.x = f2b(acc[i][0]+bias[0]); o.y = f2b(acc[i][1]+bias[1]);
                o.z = f2b(acc[i][2]+bias[2]); o.w = f2b(acc[i][3]+bias[3]);
                *(ushort4*)((unsigned short*)Cout + (size_t)grow*64 + c0) = o;
            } else {
                float4 o = make_float4(acc[i][0]+bias[0], acc[i][1]+bias[1],
                                       acc[i][2]+bias[2], acc[i][3]+bias[3]);
                *(float4*)((float*)Cout + (size_t)grow*64 + c0) = o;
            }
        }
    }
    if constexpr (WITH_SCORES){
        float as[4], ad[4];
        #pragma unroll
        for(int j=0;j<4;j++){
            as[j] = ldin(attnb, aoff + c0+j, wf32);
            ad[j] = ldin(attnb, aoff + 64+c0+j, wf32);
        }
        #pragma unroll
        for(int i=0;i<4;i++){
            float ps = 0.f, pd = 0.f;
            #pragma unroll
            for(int j=0;j<4;j++){ ps = fmaf(acc[i][j], as[j], ps); pd = fmaf(acc[i][j], ad[j], pd); }
            for(int off=1; off<16; off<<=1){
                ps += __shfl_xor(ps, off, 64);
                pd += __shfl_xor(pd, off, 64);
            }
            int grow = block_row + r0 + i;
            if((t & 15) == 0 && grow < NODES){ s_src[grow] = ps; s_dst[grow] = pd; }
        }
    }
}

// ---------------- edge-parallel logits + online (m,z) ----------------
__global__ __launch_bounds__(256) void k_edge_l(const int* __restrict__ col,
    const int* __restrict__ did, const float* __restrict__ ssrc,
    const float* __restrict__ sdst, float* __restrict__ l, float2* __restrict__ bmz)
{
    int tid = blockIdx.x*256 + threadIdx.x;
    int stride = gridDim.x*256;
    float m = SENTINEL, z = 0.f;
    for(int e = tid; e < EDGES; e += stride){
        float v = ssrc[col[e]] + sdst[did[e]];
        v = (v > 0.f) ? v : NEG_BIG_F;
        l[e] = v;
        if(v > m){ z = z*__expf(m - v) + 1.f; m = v; }
        else     { z += __expf(v - m); }
    }
    for(int off=1; off<64; off<<=1){
        float m2 = __shfl_xor(m, off, 64), z2 = __shfl_xor(z, off, 64);
        float M = fmaxf(m, m2);
        z = z*__expf(m - M) + z2*__expf(m2 - M);
        m = M;
    }
    __shared__ float sm[4], sz[4];
    int w = threadIdx.x >> 6;
    if((threadIdx.x & 63) == 0){ sm[w] = m; sz[w] = z; }
    __syncthreads();
    if(threadIdx.x == 0){
        for(int i=1;i<4;i++){
            float M = fmaxf(m, sm[i]);
            z = z*__expf(m - M) + sz[i]*__expf(sm[i] - M);
            m = M;
        }
        bmz[blockIdx.x] = make_float2(m, z);
    }
}

__global__ __launch_bounds__(256) void k_merge_mz(const float2* __restrict__ bmz, float2* __restrict__ MZ){
    int t = threadIdx.x;
    float m = SENTINEL, z = 0.f;
    for(int i = t; i < MZB; i += 256){
        float2 e = bmz[i];
        float M = fmaxf(m, e.x);
        z = z*__expf(m - M) + e.y*__expf(e.x - M);
        m = M;
    }
    for(int off=1; off<64; off<<=1){
        float m2 = __shfl_xor(m, off, 64), z2 = __shfl_xor(z, off, 64);
        float M = fmaxf(m, m2);
        z = z*__expf(m - M) + z2*__expf(m2 - M);
        m = M;
    }
    __shared__ float sm[4], sz[4];
    int w = t >> 6;
    if((t & 63) == 0){ sm[w] = m; sz[w] = z; }
    __syncthreads();
    if(t == 0){
        for(int i=1;i<4;i++){
            float M = fmaxf(m, sm[i]);
            z = z*__expf(m - M) + sz[i]*__expf(sm[i] - M);
            m = M;
        }
        MZ[0] = make_float2(m, 1.0f / z);
    }
}

// ---------------- att[e] = exp(l[e]-M)*invZ, in place over l ----------------
__global__ __launch_bounds__(256) void k_att(float* __restrict__ l, const float2* __restrict__ MZ){
    float2 mz = *MZ;
    float M = mz.x, invZ = mz.y;
    int tid = blockIdx.x*256 + threadIdx.x;
    int stride = gridDim.x*256;
    for(int e = tid; e < EDGES; e += stride)
        l[e] = __expf(l[e] - M) * invZ;
}

// ---------------- aggregation: wave/node, 64-edge coalesced batch + shuffle broadcast ----------------
__global__ __launch_bounds__(256) void k_aggregate(const unsigned short* __restrict__ wh16,
    const int* __restrict__ row_start, const int* __restrict__ col,
    const float* __restrict__ att, float* __restrict__ hout)
{
    int gw = (blockIdx.x*256 + threadIdx.x) >> 6;
    int lane = threadIdx.x & 63;
    if(gw >= NODES) return;
    int beg = row_start[gw], end = row_start[gw+1];
    int g  = lane >> 3;           // edge-group 0..7
    int c8 = (lane & 7) * 8;      // feature slice base
    float acc[8] = {0.f,0.f,0.f,0.f,0.f,0.f,0.f,0.f};
    for(int base = beg; base < end; base += 64){
        int idx = base + lane;
        bool vld = idx < end;
        int   s_l = vld ? col[idx] : 0;
        float a_l = vld ? att[idx] : 0.f;   // precomputed att (exp removed from loop)
        int n = end - base; if(n > 64) n = 64;
        int jmax = (n + 7) >> 3;
        for(int j = 0; j < jmax; j++){
            int k = 8*j + g;
            float a = __shfl(a_l, k, 64);
            int   s = __shfl(s_l, k, 64);
            if(a != 0.f){
                uint4 u = *(const uint4*)&wh16[(size_t)s*64 + c8];
                acc[0] = fmaf(a, bits2f(u.x & 0xffffu), acc[0]);
                acc[1] = fmaf(a, bits2f(u.x >> 16),     acc[1]);
                acc[2] = fmaf(a, bits2f(u.y & 0xffffu), acc[2]);
                acc[3] = fmaf(a, bits2f(u.y >> 16),     acc[3]);
                acc[4] = fmaf(a, bits2f(u.z & 0xffffu), acc[4]);
                acc[5] = fmaf(a, bits2f(u.z >> 16),     acc[5]);
                acc[6] = fmaf(a, bits2f(u.w & 0xffffu), acc[6]);
                acc[7] = fmaf(a, bits2f(u.w >> 16),     acc[7]);
            }
        }
    }
    #pragma unroll
    for(int i=0;i<8;i++){
        acc[i] += __shfl_xor(acc[i], 8, 64);
        acc[i] += __shfl_xor(acc[i], 16, 64);
        acc[i] += __shfl_xor(acc[i], 32, 64);
    }
    if(lane < 8){
        float o[8];
        #pragma unroll
        for(int i=0;i<8;i++) o[i] = elu_fast(acc[i]);
        *(float4*)&hout[(size_t)gw*64 + c8 + 0] = make_float4(o[0],o[1],o[2],o[3]);
        *(float4*)&hout[(size_t)gw*64 + c8 + 4] = make_float4(o[4],o[5],o[6],o[7]);
    }
}

// ---------------- fused out-proj + elu + log_softmax, GEMM-tiled (fp32 output) ----------------
__global__ __launch_bounds__(256) void k_out(const float* __restrict__ h,
    const void* __restrict__ Wo, const void* __restrict__ bo,
    const int* __restrict__ flags, float* __restrict__ out)
{
    __shared__ float Ht[64][65];
    __shared__ float Wsh[64][44];
    __shared__ float logits[64][44];
    __shared__ float rlz[64];
    bool f32 = flags[0] != 0;
    int t = threadIdx.x;
    int block_row = blockIdx.x * 64;

    for(int i = t; i < 64*NCLS; i += 256){
        Wsh[i/NCLS][i%NCLS] = ldin(Wo, i, f32);
    }
    {
        int r_load = t >> 2, q = t & 3;
        int grow = block_row + r_load;
        const float4* hv = (const float4*)h;
        #pragma unroll
        for(int i = 0; i < 4; i++){
            int vi = q + 4*i;
            float4 u = make_float4(0.f,0.f,0.f,0.f);
            if(grow < NODES) u = hv[(size_t)grow*16 + vi];
            Ht[vi*4+0][r_load] = u.x; Ht[vi*4+1][r_load] = u.y;
            Ht[vi*4+2][r_load] = u.z; Ht[vi*4+3][r_load] = u.w;
        }
    }
    __syncthreads();

    int cg = t & 15, rg = t >> 4;
    int c0 = cg * 4, r0 = rg * 4;
    if(cg < 10){
        float acc[4][4] = {{0.f,0.f,0.f,0.f},{0.f,0.f,0.f,0.f},{0.f,0.f,0.f,0.f},{0.f,0.f,0.f,0.f}};
        #pragma unroll 8
        for(int k = 0; k < 64; k++){
            float4 a = *(const float4*)&Ht[k][r0];
            float4 w = *(const float4*)&Wsh[k][c0];
            float av4[4] = {a.x,a.y,a.z,a.w};
            float wv4[4] = {w.x,w.y,w.z,w.w};
            #pragma unroll
            for(int i=0;i<4;i++)
                #pragma unroll
                for(int j=0;j<4;j++)
                    acc[i][j] = fmaf(av4[i], wv4[j], acc[i][j]);
        }
        float b[4];
        #pragma unroll
        for(int j=0;j<4;j++) b[j] = ldin(bo, c0+j, f32);
        #pragma unroll
        for(int i=0;i<4;i++)
            #pragma unroll
            for(int j=0;j<4;j++){
                logits[r0+i][c0+j] = elu_fast(acc[i][j] + b[j]);
            }
    }
    __syncthreads();

    {
        int r = t >> 2, qq = t & 3;
        float m = SENTINEL;
        #pragma unroll
        for(int i=0;i<10;i++) m = fmaxf(m, logits[r][qq*10 + i]);
        m = fmaxf(m, __shfl_xor(m, 1, 64));
        m = fmaxf(m, __shfl_xor(m, 2, 64));
        float s = 0.f;
        #pragma unroll
        for(int i=0;i<10;i++) s += __expf(logits[r][qq*10 + i] - m);
        s += __shfl_xor(s, 1, 64);
        s += __shfl_xor(s, 2, 64);
        if(qq == 0) rlz[r] = m + logf(s);
    }
    __syncthreads();

    for(int i = t; i < 64*NCLS; i += 256){
        int rr = i / NCLS, cc = i % NCLS;
        if(block_row + rr < NODES)
            out[(size_t)(block_row)*NCLS + i] = logits[rr][cc] - rlz[rr];
    }
}

extern "C" void kernel_launch(void* const* d_in, const int* in_sizes, int n_in,
                              void* d_out, int out_size, void* d_ws, size_t ws_size,
                              hipStream_t stream)
{
    const void* x      = d_in[0];
    const int*  ei     = (const int*)d_in[1];
    const void* emb_w  = d_in[2];
    const void* emb_b  = d_in[3];
    const void* Ws     = d_in[4];
    const void* attn_a = d_in[5];
    const void* out_w  = d_in[6];
    const void* out_b  = d_in[7];
    float* out = (float*)d_out;

    char* ws = (char*)d_ws;
    size_t off = 0;
    auto alloc = [&](size_t bytes)->char*{
        char* p = ws + off;
        off = (off + bytes + 255) & ~(size_t)255;
        return p;
    };
    int*    flags   = (int*)   alloc(256);
    float*  h       = (float*) alloc((size_t)NODES*HID*4);   // aliased as phase-A tmp
    unsigned short* wh16 = (unsigned short*)alloc((size_t)NODES*HID*2);
    float*  ssrc    = (float*) alloc((size_t)NODES*4);
    float*  sdst    = (float*) alloc((size_t)NODES*4);
    int*    rowst   = (int*)   alloc((size_t)(NODES+1)*4);
    int*    col     = (int*)   alloc((size_t)EDGES*4);
    int*    did     = (int*)   alloc((size_t)EDGES*4);
    float*  l       = (float*) alloc((size_t)EDGES*4);
    int*    bdeg    = (int*)   alloc(NBUCK*4);
    int*    bstart  = (int*)   alloc((NBUCK+1)*4);
    int*    bcursor = (int*)   alloc(NBUCK*4);
    float2* bmz     = (float2*)alloc(MZB*8);
    float2* MZ      = (float2*)alloc(16);

    int2* tmp = (int2*)h;   // consumed before k_gemm writes h

    k_detect<<<1, 256, 0, stream>>>((const unsigned*)x, (const unsigned*)ei, flags);

    hipMemsetAsync(bdeg, 0, NBUCK*4, stream);
    k_bhist<<<256, 256, 0, stream>>>(ei, flags, bdeg);
    k_bscan<<<1, 64, 0, stream>>>(bdeg, bstart, bcursor);
    k_bucket_scatter<<<NCHUNK, 256, 0, stream>>>(ei, flags, bcursor, tmp);
    k_bucket_sort<<<NBUCK, 512, 0, stream>>>(tmp, bstart, col, did, rowst);

    k_gemm<INDIM, 0, true, false, false><<<(NODES+63)/64, 256, 0, stream>>>(
        x, emb_w, 0, emb_b, nullptr, 0, flags, h, nullptr, nullptr);

    for(int lyr=0; lyr<2; lyr++){
        k_gemm<HID, 2, false, true, true><<<(NODES+63)/64, 256, 0, stream>>>(
            h, Ws, lyr*HID*HID, nullptr, attn_a, lyr*2*HID, flags, wh16, ssrc, sdst);
        k_edge_l  <<<MZB, 256, 0, stream>>>(col, did, ssrc, sdst, l, bmz);
        k_merge_mz<<<1, 256, 0, stream>>>(bmz, MZ);
        k_att     <<<MZB, 256, 0, stream>>>(l, MZ);
        k_aggregate<<<(NODES+3)/4, 256, 0, stream>>>(wh16, rowst, col, l, h);
    }

    k_out<<<(NODES+63)/64, 256, 0, stream>>>(h, out_w, out_b, flags, out);
}